// Round 2
// baseline (427.712 us; speedup 1.0000x reference)
//
#include <hip/hip_runtime.h>

// Shapes fixed by the reference setup: B=32, N=64, L=128, D=256.
#define BB 32
#define NN 64
#define LL 128
#define DD 256
#define NBTOT (BB * NN)     // 2048
#define MAX_LEN (NN * LL)   // 8192
#define D4 (DD / 4)         // 64 float4 per row

typedef float f32x4 __attribute__((ext_vector_type(4)));

// ---------------------------------------------------------------------------
// Kernel 1: per-batch inclusive prefix sum of lengths (wave64 scan),
// writes cum[b][n], inv_total[b], lengths_out[b]; zeros encoder_hidden.
// ---------------------------------------------------------------------------
__global__ __launch_bounds__(64) void prefix_kernel(
    const int* __restrict__ lengths,
    int* __restrict__ cum,          // ws: [B][N]
    float* __restrict__ inv_total,  // ws: [B]
    float* __restrict__ lengths_out,// out3: [B]
    float* __restrict__ enc_hidden) // out2: [B][D] (zero-init here)
{
    const int b = blockIdx.x;
    const int lane = threadIdx.x;

    int v = lengths[b * NN + lane];
    #pragma unroll
    for (int s = 1; s < 64; s <<= 1) {
        int o = __shfl_up(v, s, 64);
        if (lane >= s) v += o;
    }
    cum[b * NN + lane] = v;

    const int total = __shfl(v, 63, 64);
    if (lane == 0) {
        lengths_out[b] = (float)total;
        inv_total[b] = (total > 0) ? (1.0f / (float)total) : 0.0f;
    }
    #pragma unroll
    for (int k = 0; k < DD / 64; ++k)
        enc_hidden[b * DD + k * 64 + lane] = 0.0f;
}

// ---------------------------------------------------------------------------
// Kernel 2: zero-fill of the padded tail of mb_out, in LINEAR row order.
// mb_out is [t][b][ch]; row r = t*32 + b. A row is zero iff t >= total[b].
// For t >= max_b(total) (~44% of the buffer) every row hits, so the stores
// form one perfectly sequential pure-write stream -> should run at the same
// ~6.3 TB/s the harness's fillBuffer achieves, instead of the ~4.6 TB/s
// mixed rate this traffic paid when interleaved with the gather's reads.
// grid = 1024 blocks x 256 thr; each wave owns 64 consecutive rows (64 KB).
// ---------------------------------------------------------------------------
__global__ __launch_bounds__(256) void zfill_kernel(
    const int* __restrict__ cum,    // [B][N]
    f32x4* __restrict__ mb_out)     // [MAX_LEN][B][D] as float4
{
    __shared__ int s_tot[BB];
    const int tid  = threadIdx.x;
    const int wave = tid >> 6;
    const int lane = tid & 63;

    if (tid < BB) s_tot[tid] = cum[tid * NN + NN - 1];
    __syncthreads();

    // wave-level min(total) for a cheap early-out of all-valid blocks
    int m = s_tot[lane & (BB - 1)];
    #pragma unroll
    for (int s = 16; s >= 1; s >>= 1) {
        int o = __shfl_xor(m, s, 64);
        m = o < m ? o : m;
    }

    const int r0 = blockIdx.x * 256 + wave * 64;   // first row of this wave
    if (((r0 + 63) >> 5) < m) return;              // whole range valid -> no zeros

    const f32x4 z = {0.f, 0.f, 0.f, 0.f};
    #pragma unroll
    for (int j = 0; j < 64; ++j) {
        const int r = r0 + j;
        const int b = r & (BB - 1);
        const int t = r >> 5;
        if (t >= s_tot[b])
            __builtin_nontemporal_store(z, &mb_out[(size_t)r * D4 + lane]);
    }
}

// ---------------------------------------------------------------------------
// Kernel 3: gather of VALID rows only + fused masked mean + src_out.
// grid = (MAX_LEN/256, B); block = 256 threads = 4 waves.
// Balanced ~1:1 read:write mixed stream; the pure-write tail now lives in
// zfill_kernel.
// ---------------------------------------------------------------------------
__global__ __launch_bounds__(256) void gather_kernel(
    const float* __restrict__ src,       // [L][NB]
    const f32x4* __restrict__ mb,        // [L][NB][D] as float4
    const int* __restrict__ recover,     // [NB]
    const int* __restrict__ cum,         // [B][N]
    const float* __restrict__ inv_total, // [B]
    float* __restrict__ src_out,         // [MAX_LEN][B]
    f32x4* __restrict__ mb_out,          // [MAX_LEN][B][D] as float4
    float* __restrict__ enc_hidden)      // [B][D] (atomic accumulate)
{
    __shared__ int   s_cum[NN];
    __shared__ float s_accw[4][DD];      // per-wave partial sums

    const int b    = blockIdx.y;
    const int t0   = blockIdx.x * 256;
    const int tid  = threadIdx.x;
    const int wave = tid >> 6;
    const int lane = tid & 63;

    if (tid < NN) s_cum[tid] = cum[b * NN + tid];
    __syncthreads();

    const int total = s_cum[NN - 1];
    const int my_t  = t0 + tid;

    // n = number of cum entries <= my_t (node index of position my_t)
    int n = 0;
    #pragma unroll
    for (int s = 32; s >= 1; s >>= 1) {
        const int cand = n + s;
        if (cand <= NN && s_cum[cand - 1] <= my_t) n = cand;
    }
    const int l = my_t - ((n > 0) ? s_cum[n - 1] : 0);

    // row index into mb for this thread's output position (garbage if invalid,
    // never consumed in that case)
    const int rowidx = l * NBTOT + b * NN + n;

    // src_out: 1.0 in padding (reference inits with ones). Scalar gather,
    // tiny (1 MB) — stays in L2.
    float sv = 1.0f;
    if (my_t < total) sv = src[(size_t)l * NBTOT + recover[b * NN + n]];
    src_out[(size_t)my_t * BB + b] = sv;

    // ---- streaming loop: wave handles valid rows t in [wbase, wbase+64) ----
    const int wbase = t0 + wave * 64;
    int nval = total - wbase;
    nval = nval < 0 ? 0 : (nval > 64 ? 64 : nval);

    const size_t obase = ((size_t)wbase * BB + b) * D4 + lane;
    const int OSTRIDE = BB * D4;  // 2048 f32x4 per t row

    f32x4 acc = {0.f, 0.f, 0.f, 0.f};

    int j = 0;
    // 8-deep batched segment: 8 outstanding row loads before any store.
    for (; j + 8 <= nval; j += 8) {
        int r[8];
        f32x4 v[8];
        #pragma unroll
        for (int k = 0; k < 8; ++k)
            r[k] = __shfl(rowidx, j + k, 64);         // wave-uniform row index
        #pragma unroll
        for (int k = 0; k < 8; ++k)
            v[k] = __builtin_nontemporal_load(&mb[(size_t)r[k] * D4 + lane]);
        #pragma unroll
        for (int k = 0; k < 8; ++k) {
            acc += v[k];
            __builtin_nontemporal_store(
                v[k], &mb_out[obase + (size_t)(j + k) * OSTRIDE]);
        }
    }
    for (; j < nval; ++j) {
        const int r = __shfl(rowidx, j, 64);
        f32x4 v = __builtin_nontemporal_load(&mb[(size_t)r * D4 + lane]);
        acc += v;
        __builtin_nontemporal_store(v, &mb_out[obase + (size_t)j * OSTRIDE]);
    }
    // (zero tail handled by zfill_kernel)

    // per-wave private LDS rows (no atomics), then cross-wave reduce
    s_accw[wave][lane * 4 + 0] = acc.x;
    s_accw[wave][lane * 4 + 1] = acc.y;
    s_accw[wave][lane * 4 + 2] = acc.z;
    s_accw[wave][lane * 4 + 3] = acc.w;
    __syncthreads();

    const float partial = s_accw[0][tid] + s_accw[1][tid]
                        + s_accw[2][tid] + s_accw[3][tid];
    atomicAdd(&enc_hidden[b * DD + tid], partial * inv_total[b]);
}

// ---------------------------------------------------------------------------
extern "C" void kernel_launch(void* const* d_in, const int* in_sizes, int n_in,
                              void* d_out, int out_size, void* d_ws, size_t ws_size,
                              hipStream_t stream) {
    const float* src     = (const float*)d_in[0];   // [L, NB, 1]
    const float* mb      = (const float*)d_in[1];   // [L, NB, D]
    const int*   lengths = (const int*)d_in[2];     // [NB]
    const int*   recover = (const int*)d_in[3];     // [NB]

    float* out = (float*)d_out;
    float* src_out     = out;                                   // 262144
    float* mb_out      = out + (size_t)MAX_LEN * BB;            // 67108864
    float* enc_hidden  = mb_out + (size_t)MAX_LEN * BB * DD;    // 8192
    float* lengths_out = enc_hidden + (size_t)BB * DD;          // 32

    int*   cum       = (int*)d_ws;
    float* inv_total = (float*)((char*)d_ws + NBTOT * sizeof(int));

    prefix_kernel<<<BB, 64, 0, stream>>>(lengths, cum, inv_total,
                                         lengths_out, enc_hidden);

    // pure-write phase: zero the padded tail of mb_out in linear row order
    zfill_kernel<<<(MAX_LEN * BB) / 256, 256, 0, stream>>>(cum, (f32x4*)mb_out);

    // mixed phase: valid-row gather + fused mean
    dim3 grid(MAX_LEN / 256, BB);
    gather_kernel<<<grid, 256, 0, stream>>>(src, (const f32x4*)mb, recover,
                                            cum, inv_total,
                                            src_out, (f32x4*)mb_out,
                                            enc_hidden);
}